// Round 1
// baseline (8441.587 us; speedup 1.0000x reference)
//
#include <hip/hip_runtime.h>
#include <cstdint>
#include <cstddef>

// ---------------- problem constants ----------------
#define PPF   576
#define TPF   578
#define DMODEL 768
#define VD    1024
#define NLAY  12
#define NHEAD 12
#define HDIM  64
#define FFDIM 3072
#define TFRM  8
#define SEQ   4624           // TFRM*TPF
#define MVIS  4608           // TFRM*PPF

typedef unsigned short u16;
typedef unsigned int   u32;
typedef __bf16 bf16_t;
typedef bf16_t bf16x8 __attribute__((ext_vector_type(8)));
typedef float  f32x4  __attribute__((ext_vector_type(4)));

#define NEG_INF (-__builtin_inff())

__device__ __forceinline__ u16 f2bf(float f) {
  u32 u = __builtin_bit_cast(u32, f);
  return (u16)((u + 0x7fffu + ((u >> 16) & 1u)) >> 16);
}
__device__ __forceinline__ f32x4 mfma_bf16(bf16x8 a, bf16x8 b, f32x4 c) {
  return __builtin_amdgcn_mfma_f32_16x16x32_bf16(a, b, c, 0, 0, 0);
}

// ---------------- fp32 -> bf16 bulk cast (visual tokens) ----------------
__global__ __launch_bounds__(256) void cast_bf16_kernel(
    const float* __restrict__ in, u16* __restrict__ out, int n8) {
  int i = blockIdx.x * 256 + threadIdx.x;
  if (i >= n8) return;
  const float4* p = (const float4*)in + (size_t)i * 2;
  float4 a = p[0], b = p[1];
  uint4 o;
  o.x = (u32)f2bf(a.x) | ((u32)f2bf(a.y) << 16);
  o.y = (u32)f2bf(a.z) | ((u32)f2bf(a.w) << 16);
  o.z = (u32)f2bf(b.x) | ((u32)f2bf(b.y) << 16);
  o.w = (u32)f2bf(b.z) | ((u32)f2bf(b.w) << 16);
  ((uint4*)out)[i] = o;
}

// ---------------- action/state projection + RoPE -> x rows t*578+{0,1} ----------------
__global__ __launch_bounds__(256) void actsta_kernel(
    const float* __restrict__ actions, const float* __restrict__ states,
    const float* __restrict__ aw, const float* __restrict__ ab,
    const float* __restrict__ sw, const float* __restrict__ sb,
    float* __restrict__ x) {
  int t = blockIdx.x >> 1, which = blockIdx.x & 1;
  const float* in = which ? (states + t * 7) : (actions + t * 7);
  const float* W  = which ? sw : aw;
  const float* bb = which ? sb : ab;
  float iv[7];
#pragma unroll
  for (int a = 0; a < 7; a++) iv[a] = in[a];
  float* xr = x + (size_t)(t * TPF + which) * DMODEL;
  for (int i = threadIdx.x; i < DMODEL / 2; i += 256) {
    float e = bb[2 * i], o = bb[2 * i + 1];
#pragma unroll
    for (int a = 0; a < 7; a++) {
      e += iv[a] * W[(2 * i) * 7 + a];
      o += iv[a] * W[(2 * i + 1) * 7 + a];
    }
    // inv_freq = 10000^(-2i/768)
    float freq = __expf((-2.0f * (float)i / 768.0f) * 9.210340371976184f);
    float ang = (float)t * freq;
    float sn = sinf(ang), cs = cosf(ang);
    xr[2 * i]     = e * cs - o * sn;
    xr[2 * i + 1] = e * sn + o * cs;
  }
}

// ---------------- LayerNorm: fp32 x -> bf16 h (optionally framed-row gather) ----------------
__global__ __launch_bounds__(256) void ln_kernel(
    const float* __restrict__ x, u16* __restrict__ h,
    const float* __restrict__ g, const float* __restrict__ b, int framed) {
  int row = blockIdx.x;
  int src = framed ? ((row / PPF) * TPF + 2 + (row % PPF)) : row;
  const float* xr = x + (size_t)src * DMODEL;
  int tid = threadIdx.x;
  float v0 = xr[tid], v1 = xr[tid + 256], v2 = xr[tid + 512];
  float s  = v0 + v1 + v2;
  float s2 = v0 * v0 + v1 * v1 + v2 * v2;
#pragma unroll
  for (int off = 32; off > 0; off >>= 1) {
    s  += __shfl_down(s, off);
    s2 += __shfl_down(s2, off);
  }
  __shared__ float red[8];
  int wv = tid >> 6;
  if ((tid & 63) == 0) { red[wv] = s; red[4 + wv] = s2; }
  __syncthreads();
  s  = red[0] + red[1] + red[2] + red[3];
  s2 = red[4] + red[5] + red[6] + red[7];
  float mu  = s * (1.0f / DMODEL);
  float var = s2 * (1.0f / DMODEL) - mu * mu;
  float rs  = rsqrtf(var + 1e-5f);
  u16* hr = h + (size_t)row * DMODEL;
  hr[tid]       = f2bf((v0 - mu) * rs * g[tid]       + b[tid]);
  hr[tid + 256] = f2bf((v1 - mu) * rs * g[tid + 256] + b[tid + 256]);
  hr[tid + 512] = f2bf((v2 - mu) * rs * g[tid + 512] + b[tid + 512]);
}

// ---------------- bf16 MFMA GEMM, TN form: out[M,N] = A[M,K] * B[N,K]^T ----------------
// A: bf16 activations. B: fp32 weights converted to bf16 during LDS staging.
enum { EPI_BF = 0, EPI_GELU = 1, EPI_RES = 2, EPI_VIS = 3, EPI_OUT = 4 };

template <int EPI>
__global__ __launch_bounds__(256) void gemm_bt(
    const u16* __restrict__ A, const float* __restrict__ B,
    const float* __restrict__ bias, u16* __restrict__ outb,
    float* __restrict__ outf, const float* __restrict__ fe,
    int M, int N, int K) {
  __shared__ u16 As[128 * 40];   // 128 rows x 32 cols, pad to 40 (2-way free)
  __shared__ u16 Bs[128 * 40];
  const int tid = threadIdx.x;
  const int m0 = blockIdx.x * 128, n0 = blockIdx.y * 128;
  const int lr = tid >> 1, lc = (tid & 1) * 16;
  const int wv = tid >> 6, lane = tid & 63;
  const int fm = lane & 15, fq = lane >> 4;
  const int moff = (wv & 1) * 64, noff = (wv >> 1) * 64;

  f32x4 acc[4][4];
#pragma unroll
  for (int i = 0; i < 4; i++)
#pragma unroll
    for (int j = 0; j < 4; j++) acc[i][j] = f32x4{0.f, 0.f, 0.f, 0.f};

  const bool aval = (m0 + lr) < M;
  const u16*   aptr = A + (size_t)(aval ? (m0 + lr) : 0) * K + lc;
  const float* bptr = B + (size_t)(n0 + lr) * K + lc;

  for (int k0 = 0; k0 < K; k0 += 32) {
    uint4 a0 = {0, 0, 0, 0}, a1 = {0, 0, 0, 0};
    if (aval) {
      a0 = *(const uint4*)(aptr + k0);
      a1 = *(const uint4*)(aptr + k0 + 8);
    }
    *(uint4*)&As[lr * 40 + lc]     = a0;
    *(uint4*)&As[lr * 40 + lc + 8] = a1;
    float4 b0 = *(const float4*)(bptr + k0);
    float4 b1 = *(const float4*)(bptr + k0 + 4);
    float4 b2 = *(const float4*)(bptr + k0 + 8);
    float4 b3 = *(const float4*)(bptr + k0 + 12);
    uint4 p0, p1;
    p0.x = (u32)f2bf(b0.x) | ((u32)f2bf(b0.y) << 16);
    p0.y = (u32)f2bf(b0.z) | ((u32)f2bf(b0.w) << 16);
    p0.z = (u32)f2bf(b1.x) | ((u32)f2bf(b1.y) << 16);
    p0.w = (u32)f2bf(b1.z) | ((u32)f2bf(b1.w) << 16);
    p1.x = (u32)f2bf(b2.x) | ((u32)f2bf(b2.y) << 16);
    p1.y = (u32)f2bf(b2.z) | ((u32)f2bf(b2.w) << 16);
    p1.z = (u32)f2bf(b3.x) | ((u32)f2bf(b3.y) << 16);
    p1.w = (u32)f2bf(b3.z) | ((u32)f2bf(b3.w) << 16);
    *(uint4*)&Bs[lr * 40 + lc]     = p0;
    *(uint4*)&Bs[lr * 40 + lc + 8] = p1;
    __syncthreads();
    bf16x8 af[4], bfv[4];
#pragma unroll
    for (int mi = 0; mi < 4; mi++)
      af[mi] = *(const bf16x8*)&As[(moff + mi * 16 + fm) * 40 + fq * 8];
#pragma unroll
    for (int ni = 0; ni < 4; ni++)
      bfv[ni] = *(const bf16x8*)&Bs[(noff + ni * 16 + fm) * 40 + fq * 8];
#pragma unroll
    for (int mi = 0; mi < 4; mi++)
#pragma unroll
      for (int ni = 0; ni < 4; ni++)
        acc[mi][ni] = mfma_bf16(af[mi], bfv[ni], acc[mi][ni]);
    __syncthreads();
  }

  // epilogue: element (row = quad*4+reg, col = lane&15) per 16x16 tile
#pragma unroll
  for (int mi = 0; mi < 4; mi++) {
#pragma unroll
    for (int r = 0; r < 4; r++) {
      int gr = m0 + moff + mi * 16 + fq * 4 + r;
      if (gr >= M) continue;
#pragma unroll
      for (int ni = 0; ni < 4; ni++) {
        int gc = n0 + noff + ni * 16 + fm;
        float v = acc[mi][ni][r] + bias[gc];
        if constexpr (EPI == EPI_BF) {
          outb[(size_t)gr * N + gc] = f2bf(v);
        } else if constexpr (EPI == EPI_GELU) {
          float gl = 0.5f * v * (1.0f + erff(v * 0.70710678118654752f));
          outb[(size_t)gr * N + gc] = f2bf(gl);
        } else if constexpr (EPI == EPI_RES) {
          outf[(size_t)gr * N + gc] += v;
        } else if constexpr (EPI == EPI_VIS) {
          int t = gr / PPF, p = gr % PPF;
          outf[(size_t)(t * TPF + 2 + p) * DMODEL + gc] = v + fe[(size_t)t * DMODEL + gc];
        } else {  // EPI_OUT
          outf[(size_t)gr * N + gc] = v;
        }
      }
    }
  }
}

// ---------------- flash attention: block = (128 q-rows, head) ----------------
__global__ __launch_bounds__(256) void attn_kernel(
    const u16* __restrict__ qkv, u16* __restrict__ ctx) {
  __shared__ u16 Ks[64 * 72];        // [k][d], pad 72
  __shared__ u16 Vs[64 * 72];        // transposed: [d][k], pad 72
  __shared__ u16 Ps[4 * 32 * 72];    // per-wave P [q_local][k], pad 72
  const int qt = blockIdx.x, hd = blockIdx.y;
  const int tid = threadIdx.x, wv = tid >> 6, lane = tid & 63;
  const int fm = lane & 15, fq = lane >> 4;
  const int q0 = qt * 128 + wv * 32;
  const float scale = 0.125f;  // 1/sqrt(64)

  // Q fragments (reused over all kv tiles)
  bf16x8 qf[2][2];
#pragma unroll
  for (int mi = 0; mi < 2; mi++)
#pragma unroll
    for (int kk = 0; kk < 2; kk++) {
      int qr = min(q0 + mi * 16 + fm, SEQ - 1);
      qf[mi][kk] = *(const bf16x8*)&qkv[(size_t)qr * 2304 + hd * 64 + kk * 32 + fq * 8];
    }
  int lim[2][4];
#pragma unroll
  for (int mi = 0; mi < 2; mi++)
#pragma unroll
    for (int r = 0; r < 4; r++) {
      int qr = min(q0 + mi * 16 + fq * 4 + r, SEQ - 1);
      lim[mi][r] = (qr / TPF + 1) * TPF;
    }
  f32x4 o[2][4];
  float mrow[2][4], lrow[2][4];
#pragma unroll
  for (int mi = 0; mi < 2; mi++) {
#pragma unroll
    for (int di = 0; di < 4; di++) o[mi][di] = f32x4{0.f, 0.f, 0.f, 0.f};
#pragma unroll
    for (int r = 0; r < 4; r++) { mrow[mi][r] = NEG_INF; lrow[mi][r] = 0.f; }
  }
  const int qmax = min(qt * 128 + 127, SEQ - 1);
  const int nkv = (qmax / TPF + 1) * TPF;
  const int wlim = (min(q0 + 31, SEQ - 1) / TPF + 1) * TPF;  // this wave's kv extent
  const int sr = tid >> 2, sc = (tid & 3) * 16;   // K staging map
  const int vk = (tid >> 3) * 2, vd = (tid & 7) * 8;  // V staging map

  for (int kb = 0; kb < nkv; kb += 64) {
    {  // stage K [k][d]
      uint4 z = {0, 0, 0, 0};
      int krow = kb + sr;
      bool ok = krow < SEQ;
      const u16* kp = qkv + (size_t)krow * 2304 + DMODEL + hd * 64 + sc;
      uint4 kv0 = ok ? *(const uint4*)kp : z;
      uint4 kv1 = ok ? *(const uint4*)(kp + 8) : z;
      *(uint4*)&Ks[sr * 72 + sc]     = kv0;
      *(uint4*)&Ks[sr * 72 + sc + 8] = kv1;
    }
    {  // stage V transposed [d][k] (paired k's packed as u32 writes)
      uint4 z = {0, 0, 0, 0};
      int kr0 = kb + vk, kr1 = kb + vk + 1;
      const u16* vp0 = qkv + (size_t)kr0 * 2304 + 2 * DMODEL + hd * 64 + vd;
      const u16* vp1 = qkv + (size_t)kr1 * 2304 + 2 * DMODEL + hd * 64 + vd;
      uint4 v0 = (kr0 < SEQ) ? *(const uint4*)vp0 : z;
      uint4 v1 = (kr1 < SEQ) ? *(const uint4*)vp1 : z;
      const u16* q0p = (const u16*)&v0;
      const u16* q1p = (const u16*)&v1;
#pragma unroll
      for (int j = 0; j < 8; j++) {
        u32 val = (u32)q0p[j] | ((u32)q1p[j] << 16);
        *(u32*)&Vs[(vd + j) * 72 + vk] = val;
      }
    }
    __syncthreads();
    if (kb < wlim) {
      // scores S[32q x 64k] = Q K^T
      f32x4 sA[2][4];
#pragma unroll
      for (int mi = 0; mi < 2; mi++)
#pragma unroll
        for (int ni = 0; ni < 4; ni++) sA[mi][ni] = f32x4{0.f, 0.f, 0.f, 0.f};
      bf16x8 kf[4][2];
#pragma unroll
      for (int ni = 0; ni < 4; ni++)
#pragma unroll
        for (int kk = 0; kk < 2; kk++)
          kf[ni][kk] = *(const bf16x8*)&Ks[(ni * 16 + fm) * 72 + kk * 32 + fq * 8];
#pragma unroll
      for (int mi = 0; mi < 2; mi++)
#pragma unroll
        for (int ni = 0; ni < 4; ni++)
#pragma unroll
          for (int kk = 0; kk < 2; kk++)
            sA[mi][ni] = mfma_bf16(qf[mi][kk], kf[ni][kk], sA[mi][ni]);
      // online softmax, rows live on 16-lane col groups (quad fixed)
#pragma unroll
      for (int mi = 0; mi < 2; mi++) {
#pragma unroll
        for (int r = 0; r < 4; r++) {
          float vv[4];
          float mx = -3.4e38f;
#pragma unroll
          for (int ni = 0; ni < 4; ni++) {
            float v = sA[mi][ni][r] * scale;
            int kidx = kb + ni * 16 + fm;
            if (kidx >= lim[mi][r]) v = NEG_INF;
            vv[ni] = v;
            mx = fmaxf(mx, v);
          }
          mx = fmaxf(mx, __shfl_xor(mx, 1));
          mx = fmaxf(mx, __shfl_xor(mx, 2));
          mx = fmaxf(mx, __shfl_xor(mx, 4));
          mx = fmaxf(mx, __shfl_xor(mx, 8));
          float mn = fmaxf(mrow[mi][r], mx);
          float al = __expf(mrow[mi][r] - mn);
          mrow[mi][r] = mn;
          float sum = 0.f;
#pragma unroll
          for (int ni = 0; ni < 4; ni++) {
            float p = __expf(vv[ni] - mn);
            sum += p;
            Ps[wv * 2304 + (mi * 16 + fq * 4 + r) * 72 + ni * 16 + fm] = f2bf(p);
          }
          sum += __shfl_xor(sum, 1);
          sum += __shfl_xor(sum, 2);
          sum += __shfl_xor(sum, 4);
          sum += __shfl_xor(sum, 8);
          lrow[mi][r] = lrow[mi][r] * al + sum;
#pragma unroll
          for (int di = 0; di < 4; di++) o[mi][di][r] *= al;
        }
      }
      // PV: O[32q x 64d] += P[32q x 64k] * V[64k x 64d]
      bf16x8 pf[2][2];
#pragma unroll
      for (int mi = 0; mi < 2; mi++)
#pragma unroll
        for (int kk = 0; kk < 2; kk++)
          pf[mi][kk] = *(const bf16x8*)&Ps[wv * 2304 + (mi * 16 + fm) * 72 + kk * 32 + fq * 8];
      bf16x8 vf[4][2];
#pragma unroll
      for (int di = 0; di < 4; di++)
#pragma unroll
        for (int kk = 0; kk < 2; kk++)
          vf[di][kk] = *(const bf16x8*)&Vs[(di * 16 + fm) * 72 + kk * 32 + fq * 8];
#pragma unroll
      for (int mi = 0; mi < 2; mi++)
#pragma unroll
        for (int di = 0; di < 4; di++)
#pragma unroll
          for (int kk = 0; kk < 2; kk++)
            o[mi][di] = mfma_bf16(pf[mi][kk], vf[di][kk], o[mi][di]);
    }
    __syncthreads();
  }
  // write ctx (bf16)
#pragma unroll
  for (int mi = 0; mi < 2; mi++)
#pragma unroll
    for (int r = 0; r < 4; r++) {
      float l = lrow[mi][r];
      float inv = (l > 0.f) ? 1.f / l : 0.f;
      int gr = q0 + mi * 16 + fq * 4 + r;
      if (gr < SEQ) {
#pragma unroll
        for (int di = 0; di < 4; di++) {
          int gc = hd * 64 + di * 16 + fm;
          ctx[(size_t)gr * DMODEL + gc] = f2bf(o[mi][di][r] * inv);
        }
      }
    }
}

// ---------------- host side ----------------
extern "C" void kernel_launch(void* const* d_in, const int* in_sizes, int n_in,
                              void* d_out, int out_size, void* d_ws, size_t ws_size,
                              hipStream_t stream) {
  const float* visual  = (const float*)d_in[0];
  const float* actions = (const float*)d_in[1];
  const float* states  = (const float*)d_in[2];
  const float* vproj_w = (const float*)d_in[3];
  const float* vproj_b = (const float*)d_in[4];
  const float* aproj_w = (const float*)d_in[5];
  const float* aproj_b = (const float*)d_in[6];
  const float* sproj_w = (const float*)d_in[7];
  const float* sproj_b = (const float*)d_in[8];
  const float* fembed  = (const float*)d_in[9];
  const float* qkv_w   = (const float*)d_in[10];
  const float* qkv_b   = (const float*)d_in[11];
  const float* ao_w    = (const float*)d_in[12];
  const float* ao_b    = (const float*)d_in[13];
  const float* ln1g    = (const float*)d_in[14];
  const float* ln1b    = (const float*)d_in[15];
  const float* ff1w    = (const float*)d_in[16];
  const float* ff1b    = (const float*)d_in[17];
  const float* ff2w    = (const float*)d_in[18];
  const float* ff2b    = (const float*)d_in[19];
  const float* ln2g    = (const float*)d_in[20];
  const float* ln2b    = (const float*)d_in[21];
  const float* ong     = (const float*)d_in[22];
  const float* onb     = (const float*)d_in[23];
  const float* opw     = (const float*)d_in[24];
  const float* opb     = (const float*)d_in[25];

  // workspace layout (total ~78.1 MB)
  char* ws = (char*)d_ws;
  float* x   = (float*)ws;  ws += (size_t)SEQ * DMODEL * 4;   // fp32 residual
  u16*  h    = (u16*)ws;    ws += (size_t)SEQ * DMODEL * 2;   // bf16 LN output
  u16*  qkvb = (u16*)ws;    ws += (size_t)SEQ * 3 * DMODEL * 2;
  u16*  ctx  = (u16*)ws;    ws += (size_t)SEQ * DMODEL * 2;
  u16*  fbuf = (u16*)ws;    ws += (size_t)SEQ * FFDIM * 2;    // FF intermediate
  u16*  visbf = fbuf;  // alias: visual bf16 only needed before layer loop

  dim3 blk(256);
  const int MT = (SEQ + 127) / 128;  // 37

  cast_bf16_kernel<<<dim3((MVIS * VD) / 8 / 256), blk, 0, stream>>>(
      visual, visbf, (MVIS * VD) / 8);
  gemm_bt<EPI_VIS><<<dim3(MVIS / 128, DMODEL / 128), blk, 0, stream>>>(
      visbf, vproj_w, vproj_b, nullptr, x, fembed, MVIS, DMODEL, VD);
  actsta_kernel<<<dim3(16), blk, 0, stream>>>(
      actions, states, aproj_w, aproj_b, sproj_w, sproj_b, x);

  for (int l = 0; l < NLAY; l++) {
    ln_kernel<<<dim3(SEQ), blk, 0, stream>>>(x, h, ln1g + l * DMODEL, ln1b + l * DMODEL, 0);
    gemm_bt<EPI_BF><<<dim3(MT, 3 * DMODEL / 128), blk, 0, stream>>>(
        h, qkv_w + (size_t)l * 3 * DMODEL * DMODEL, qkv_b + (size_t)l * 3 * DMODEL,
        qkvb, nullptr, nullptr, SEQ, 3 * DMODEL, DMODEL);
    attn_kernel<<<dim3(MT, NHEAD), blk, 0, stream>>>(qkvb, ctx);
    gemm_bt<EPI_RES><<<dim3(MT, DMODEL / 128), blk, 0, stream>>>(
        ctx, ao_w + (size_t)l * DMODEL * DMODEL, ao_b + (size_t)l * DMODEL,
        nullptr, x, nullptr, SEQ, DMODEL, DMODEL);
    ln_kernel<<<dim3(SEQ), blk, 0, stream>>>(x, h, ln2g + l * DMODEL, ln2b + l * DMODEL, 0);
    gemm_bt<EPI_GELU><<<dim3(MT, FFDIM / 128), blk, 0, stream>>>(
        h, ff1w + (size_t)l * FFDIM * DMODEL, ff1b + (size_t)l * FFDIM,
        fbuf, nullptr, nullptr, SEQ, FFDIM, DMODEL);
    gemm_bt<EPI_RES><<<dim3(MT, DMODEL / 128), blk, 0, stream>>>(
        fbuf, ff2w + (size_t)l * DMODEL * FFDIM, ff2b + (size_t)l * DMODEL,
        nullptr, x, nullptr, SEQ, DMODEL, FFDIM);
  }
  ln_kernel<<<dim3(MVIS), blk, 0, stream>>>(x, h, ong, onb, 1);
  gemm_bt<EPI_OUT><<<dim3(MVIS / 128, VD / 128), blk, 0, stream>>>(
      h, opw, opb, nullptr, (float*)d_out, nullptr, MVIS, VD, DMODEL);
}

// Round 2
// 6646.159 us; speedup vs baseline: 1.2701x; 1.2701x over previous
//
#include <hip/hip_runtime.h>
#include <cstdint>
#include <cstddef>

// ---------------- problem constants ----------------
#define PPF   576
#define TPF   578
#define DMODEL 768
#define VD    1024
#define NLAY  12
#define NHEAD 12
#define HDIM  64
#define FFDIM 3072
#define TFRM  8
#define SEQ   4624           // TFRM*TPF
#define MVIS  4608           // TFRM*PPF
#define MPAD  4736           // 37*128, padded row count
#define SPAD  4736

typedef unsigned short u16;
typedef unsigned int   u32;
typedef __bf16 bf16_t;
typedef bf16_t bf16x8 __attribute__((ext_vector_type(8)));
typedef float  f32x4  __attribute__((ext_vector_type(4)));

#define NEG_INF (-__builtin_inff())

__device__ __forceinline__ u16 f2bf(float f) {
  u32 u = __builtin_bit_cast(u32, f);
  return (u16)((u + 0x7fffu + ((u >> 16) & 1u)) >> 16);
}
__device__ __forceinline__ f32x4 mfma_bf16(bf16x8 a, bf16x8 b, f32x4 c) {
  return __builtin_amdgcn_mfma_f32_16x16x32_bf16(a, b, c, 0, 0, 0);
}

// async global->LDS, 16 B per lane; LDS dest = wave-uniform base + lane*16
typedef __attribute__((address_space(3))) unsigned int lds_u32;
typedef const __attribute__((address_space(1))) unsigned int glb_u32;
__device__ __forceinline__ void async16(const void* g, void* l) {
  __builtin_amdgcn_global_load_lds((glb_u32*)g, (lds_u32*)l, 16, 0, 0);
}

// ---------------- fp32 -> bf16 converter (two regions per launch) ----------------
__global__ __launch_bounds__(256) void conv2_kernel(
    const float* __restrict__ s1, u16* __restrict__ d1, int n1_8,
    const float* __restrict__ s2, u16* __restrict__ d2, int n2_8) {
  int i = blockIdx.x * 256 + threadIdx.x;
  const float* s;
  u16* d;
  int j;
  if (i < n1_8) {
    s = s1; d = d1; j = i;
  } else {
    j = i - n1_8;
    if (j >= n2_8) return;
    s = s2; d = d2;
  }
  const float4* p = (const float4*)s + (size_t)j * 2;
  float4 a = p[0], b = p[1];
  uint4 o;
  o.x = (u32)f2bf(a.x) | ((u32)f2bf(a.y) << 16);
  o.y = (u32)f2bf(a.z) | ((u32)f2bf(a.w) << 16);
  o.z = (u32)f2bf(b.x) | ((u32)f2bf(b.y) << 16);
  o.w = (u32)f2bf(b.z) | ((u32)f2bf(b.w) << 16);
  ((uint4*)d)[j] = o;
}

// ---------------- action/state projection + RoPE -> x rows t*578+{0,1} ----------------
__global__ __launch_bounds__(256) void actsta_kernel(
    const float* __restrict__ actions, const float* __restrict__ states,
    const float* __restrict__ aw, const float* __restrict__ ab,
    const float* __restrict__ sw, const float* __restrict__ sb,
    float* __restrict__ x) {
  int t = blockIdx.x >> 1, which = blockIdx.x & 1;
  const float* in = which ? (states + t * 7) : (actions + t * 7);
  const float* W  = which ? sw : aw;
  const float* bb = which ? sb : ab;
  float iv[7];
#pragma unroll
  for (int a = 0; a < 7; a++) iv[a] = in[a];
  float* xr = x + (size_t)(t * TPF + which) * DMODEL;
  for (int i = threadIdx.x; i < DMODEL / 2; i += 256) {
    float e = bb[2 * i], o = bb[2 * i + 1];
#pragma unroll
    for (int a = 0; a < 7; a++) {
      e += iv[a] * W[(2 * i) * 7 + a];
      o += iv[a] * W[(2 * i + 1) * 7 + a];
    }
    float freq = __expf((-2.0f * (float)i / 768.0f) * 9.210340371976184f);
    float ang = (float)t * freq;
    float sn = sinf(ang), cs = cosf(ang);
    xr[2 * i]     = e * cs - o * sn;
    xr[2 * i + 1] = e * sn + o * cs;
  }
}

// ---------------- LayerNorm: fp32 x -> bf16 h (optionally framed-row gather) ----------------
__global__ __launch_bounds__(256) void ln_kernel(
    const float* __restrict__ x, u16* __restrict__ h,
    const float* __restrict__ g, const float* __restrict__ b, int framed) {
  int row = blockIdx.x;
  int src = framed ? ((row / PPF) * TPF + 2 + (row % PPF)) : row;
  const float* xr = x + (size_t)src * DMODEL;
  int tid = threadIdx.x;
  float v0 = xr[tid], v1 = xr[tid + 256], v2 = xr[tid + 512];
  float s  = v0 + v1 + v2;
  float s2 = v0 * v0 + v1 * v1 + v2 * v2;
#pragma unroll
  for (int off = 32; off > 0; off >>= 1) {
    s  += __shfl_down(s, off);
    s2 += __shfl_down(s2, off);
  }
  __shared__ float red[8];
  int wv = tid >> 6;
  if ((tid & 63) == 0) { red[wv] = s; red[4 + wv] = s2; }
  __syncthreads();
  s  = red[0] + red[1] + red[2] + red[3];
  s2 = red[4] + red[5] + red[6] + red[7];
  float mu  = s * (1.0f / DMODEL);
  float var = s2 * (1.0f / DMODEL) - mu * mu;
  float rs  = rsqrtf(var + 1e-5f);
  u16* hr = h + (size_t)row * DMODEL;
  hr[tid]       = f2bf((v0 - mu) * rs * g[tid]       + b[tid]);
  hr[tid + 256] = f2bf((v1 - mu) * rs * g[tid + 256] + b[tid + 256]);
  hr[tid + 512] = f2bf((v2 - mu) * rs * g[tid + 512] + b[tid + 512]);
}

// ---------------- bf16 MFMA GEMM (m97 structure): out[M,N] = A[M,K] * B[N,K]^T ----------------
// Both operands bf16, staged via global_load_lds width-16 into unpadded 128x32 tiles.
// A buffers are row-padded to a multiple of 128 so staging never goes OOB.
enum { EPI_BF = 0, EPI_GELU = 1, EPI_RES = 2, EPI_VIS = 3, EPI_OUT = 4 };

template <int EPI>
__global__ __launch_bounds__(256) void gemm_bt(
    const u16* __restrict__ A, const u16* __restrict__ B,
    const float* __restrict__ bias, u16* __restrict__ outb,
    float* __restrict__ outf, const float* __restrict__ fe,
    int M, int N, int K) {
  __shared__ __align__(16) u16 As[128 * 32];
  __shared__ __align__(16) u16 Bs[128 * 32];
  const int tid = threadIdx.x;
  const int m0 = blockIdx.x * 128, n0 = blockIdx.y * 128;
  const int wv = tid >> 6, lane = tid & 63;
  const int fm = lane & 15, fq = lane >> 4;
  const int moff = (wv & 1) * 64, noff = (wv >> 1) * 64;

  f32x4 acc[4][4];
#pragma unroll
  for (int i = 0; i < 4; i++)
#pragma unroll
    for (int j = 0; j < 4; j++) acc[i][j] = f32x4{0.f, 0.f, 0.f, 0.f};

  // staging: wave wv covers rows [wv*32, wv*32+32) of each tile via 2 wave-loads
  const int srow = wv * 32 + (lane >> 2);
  const int scol = (lane & 3) * 8;
  const u16* ga = A + (size_t)(m0 + srow) * K + scol;
  const u16* gb = B + (size_t)(n0 + srow) * K + scol;
  u16* lA = As + (wv * 32) * 32;
  u16* lB = Bs + (wv * 32) * 32;
  const size_t row16 = (size_t)16 * K;

  for (int k0 = 0; k0 < K; k0 += 32) {
    async16(ga + k0,         lA);
    async16(ga + row16 + k0, lA + 16 * 32);
    async16(gb + k0,         lB);
    async16(gb + row16 + k0, lB + 16 * 32);
    __syncthreads();
    bf16x8 af[4], bfv[4];
#pragma unroll
    for (int mi = 0; mi < 4; mi++)
      af[mi] = *(const bf16x8*)&As[(moff + mi * 16 + fm) * 32 + fq * 8];
#pragma unroll
    for (int ni = 0; ni < 4; ni++)
      bfv[ni] = *(const bf16x8*)&Bs[(noff + ni * 16 + fm) * 32 + fq * 8];
#pragma unroll
    for (int mi = 0; mi < 4; mi++)
#pragma unroll
      for (int ni = 0; ni < 4; ni++)
        acc[mi][ni] = mfma_bf16(af[mi], bfv[ni], acc[mi][ni]);
    __syncthreads();
  }

#pragma unroll
  for (int mi = 0; mi < 4; mi++) {
#pragma unroll
    for (int r = 0; r < 4; r++) {
      int gr = m0 + moff + mi * 16 + fq * 4 + r;
      if (gr >= M) continue;
#pragma unroll
      for (int ni = 0; ni < 4; ni++) {
        int gc = n0 + noff + ni * 16 + fm;
        float v = acc[mi][ni][r] + bias[gc];
        if constexpr (EPI == EPI_BF) {
          outb[(size_t)gr * N + gc] = f2bf(v);
        } else if constexpr (EPI == EPI_GELU) {
          float gl = 0.5f * v * (1.0f + erff(v * 0.70710678118654752f));
          outb[(size_t)gr * N + gc] = f2bf(gl);
        } else if constexpr (EPI == EPI_RES) {
          outf[(size_t)gr * N + gc] += v;
        } else if constexpr (EPI == EPI_VIS) {
          int t = gr / PPF, p = gr % PPF;
          outf[(size_t)(t * TPF + 2 + p) * DMODEL + gc] = v + fe[(size_t)t * DMODEL + gc];
        } else {  // EPI_OUT
          outf[(size_t)gr * N + gc] = v;
        }
      }
    }
  }
}

// ---------------- V transpose: qkvb[s][1536+h*64+d] -> vt[h][d][s] ----------------
__global__ __launch_bounds__(256) void transpose_v_kernel(
    const u16* __restrict__ qkv, u16* __restrict__ vt) {
  const int hd = blockIdx.y;
  const int d = threadIdx.x & 63, sq = threadIdx.x >> 6;
  const int s0 = blockIdx.x * 128 + sq * 32;
  const u16* src = qkv + (size_t)s0 * 2304 + 2 * DMODEL + hd * 64 + d;
  u16 buf[32];
#pragma unroll
  for (int j = 0; j < 32; j++) buf[j] = src[(size_t)j * 2304];
  u16* dst = vt + (size_t)(hd * 64 + d) * SPAD + s0;
#pragma unroll
  for (int c = 0; c < 4; c++) {
    uint4 o;
    o.x = (u32)buf[c * 8 + 0] | ((u32)buf[c * 8 + 1] << 16);
    o.y = (u32)buf[c * 8 + 2] | ((u32)buf[c * 8 + 3] << 16);
    o.z = (u32)buf[c * 8 + 4] | ((u32)buf[c * 8 + 5] << 16);
    o.w = (u32)buf[c * 8 + 6] | ((u32)buf[c * 8 + 7] << 16);
    *(uint4*)(dst + c * 8) = o;
  }
}

// ---------------- flash attention: block = (128 q-rows, head), 128-key tiles ----------------
// heavy-first: qt = 36 - blockIdx.x so longest blocks dispatch first
__global__ __launch_bounds__(256) void attn_kernel(
    const u16* __restrict__ qkv, const u16* __restrict__ vt, u16* __restrict__ ctx) {
  __shared__ __align__(16) u16 Ks[128 * 64];    // [k][d], unpadded (global_load_lds)
  __shared__ __align__(16) u16 Vts[64 * 128];   // [d][k], unpadded (global_load_lds)
  __shared__ __align__(16) u16 Ps[4 * 32 * 136];  // per-wave P, pad 136 (writes <=2-way)
  const int qt = 36 - blockIdx.x, hd = blockIdx.y;
  const int tid = threadIdx.x, wv = tid >> 6, lane = tid & 63;
  const int fm = lane & 15, fq = lane >> 4;
  const int q0 = qt * 128 + wv * 32;
  const float scale2 = 0.18033688011112042f;  // (1/8) * log2(e)

  bf16x8 qf[2][2];
#pragma unroll
  for (int mi = 0; mi < 2; mi++)
#pragma unroll
    for (int kk = 0; kk < 2; kk++)
      qf[mi][kk] = *(const bf16x8*)&qkv[(size_t)(q0 + mi * 16 + fm) * 2304 + hd * 64 + kk * 32 + fq * 8];
  int lim[2][4];
#pragma unroll
  for (int mi = 0; mi < 2; mi++)
#pragma unroll
    for (int r = 0; r < 4; r++) {
      int qr = q0 + mi * 16 + fq * 4 + r;
      lim[mi][r] = (qr / TPF + 1) * TPF;
    }
  f32x4 o[2][4];
  float mrow[2][4], lrow[2][4];
#pragma unroll
  for (int mi = 0; mi < 2; mi++) {
#pragma unroll
    for (int di = 0; di < 4; di++) o[mi][di] = f32x4{0.f, 0.f, 0.f, 0.f};
#pragma unroll
    for (int r = 0; r < 4; r++) { mrow[mi][r] = NEG_INF; lrow[mi][r] = 0.f; }
  }
  const int qmax = min(qt * 128 + 127, SEQ - 1);
  const int nkv = (qmax / TPF + 1) * TPF;
  const int wlim = (min(q0 + 31, SEQ - 1) / TPF + 1) * TPF;

  // staging maps (wave-uniform LDS bases)
  u16* lK = Ks + (wv * 32) * 64;
  u16* lV = Vts + (wv * 16) * 128;
  const u16* gK = qkv + DMODEL + (size_t)hd * 64 + (size_t)(lane >> 3) * 2304 + (lane & 7) * 8;
  const u16* gV = vt + (size_t)(hd * 64 + wv * 16 + (lane >> 4)) * SPAD + (lane & 15) * 8;

  for (int kb = 0; kb < nkv; kb += 128) {
#pragma unroll
    for (int j = 0; j < 4; j++)
      async16(gK + (size_t)(kb + wv * 32 + j * 8) * 2304, lK + j * 8 * 64);
#pragma unroll
    for (int j = 0; j < 4; j++)
      async16(gV + kb + (size_t)(j * 4) * SPAD, lV + j * 4 * 128);
    __syncthreads();
    if (kb < wlim) {
      f32x4 sA[2][8];
#pragma unroll
      for (int mi = 0; mi < 2; mi++)
#pragma unroll
        for (int ni = 0; ni < 8; ni++) sA[mi][ni] = f32x4{0.f, 0.f, 0.f, 0.f};
#pragma unroll
      for (int ni = 0; ni < 8; ni++) {
        bf16x8 k0 = *(const bf16x8*)&Ks[(ni * 16 + fm) * 64 + fq * 8];
        bf16x8 k1 = *(const bf16x8*)&Ks[(ni * 16 + fm) * 64 + 32 + fq * 8];
        sA[0][ni] = mfma_bf16(qf[0][0], k0, sA[0][ni]);
        sA[0][ni] = mfma_bf16(qf[0][1], k1, sA[0][ni]);
        sA[1][ni] = mfma_bf16(qf[1][0], k0, sA[1][ni]);
        sA[1][ni] = mfma_bf16(qf[1][1], k1, sA[1][ni]);
      }
#pragma unroll
      for (int mi = 0; mi < 2; mi++) {
#pragma unroll
        for (int r = 0; r < 4; r++) {
          float vv[8];
          float mx = -3.4e38f;
#pragma unroll
          for (int ni = 0; ni < 8; ni++) {
            float v = sA[mi][ni][r] * scale2;
            int kidx = kb + ni * 16 + fm;
            if (kidx >= lim[mi][r]) v = NEG_INF;
            vv[ni] = v;
            mx = fmaxf(mx, v);
          }
          mx = fmaxf(mx, __shfl_xor(mx, 1));
          mx = fmaxf(mx, __shfl_xor(mx, 2));
          mx = fmaxf(mx, __shfl_xor(mx, 4));
          mx = fmaxf(mx, __shfl_xor(mx, 8));
          float mn = fmaxf(mrow[mi][r], mx);
          float al = exp2f(mrow[mi][r] - mn);
          mrow[mi][r] = mn;
          float sum = 0.f;
          u16* prow = &Ps[(wv * 32 + mi * 16 + fq * 4 + r) * 136 + fm];
#pragma unroll
          for (int ni = 0; ni < 8; ni++) {
            float p = exp2f(vv[ni] - mn);
            sum += p;
            prow[ni * 16] = f2bf(p);
          }
          sum += __shfl_xor(sum, 1);
          sum += __shfl_xor(sum, 2);
          sum += __shfl_xor(sum, 4);
          sum += __shfl_xor(sum, 8);
          lrow[mi][r] = lrow[mi][r] * al + sum;
#pragma unroll
          for (int di = 0; di < 4; di++) o[mi][di][r] *= al;
        }
      }
      // PV: O[32q x 64d] += P[32q x 128k] * V[128k x 64d]   (P region is wave-private)
      bf16x8 pf[2][4];
#pragma unroll
      for (int mi = 0; mi < 2; mi++)
#pragma unroll
        for (int kk = 0; kk < 4; kk++)
          pf[mi][kk] = *(const bf16x8*)&Ps[(wv * 32 + mi * 16 + fm) * 136 + kk * 32 + fq * 8];
#pragma unroll
      for (int di = 0; di < 4; di++) {
        bf16x8 vf[4];
#pragma unroll
        for (int kk = 0; kk < 4; kk++)
          vf[kk] = *(const bf16x8*)&Vts[(di * 16 + fm) * 128 + kk * 32 + fq * 8];
#pragma unroll
        for (int mi = 0; mi < 2; mi++)
#pragma unroll
          for (int kk = 0; kk < 4; kk++)
            o[mi][di] = mfma_bf16(pf[mi][kk], vf[kk], o[mi][di]);
      }
    }
    __syncthreads();
  }
#pragma unroll
  for (int mi = 0; mi < 2; mi++)
#pragma unroll
    for (int r = 0; r < 4; r++) {
      float l = lrow[mi][r];
      float inv = (l > 0.f) ? 1.f / l : 0.f;
      int gr = q0 + mi * 16 + fq * 4 + r;
      if (gr < SEQ) {
#pragma unroll
        for (int di = 0; di < 4; di++) {
          int gc = hd * 64 + di * 16 + fm;
          ctx[(size_t)gr * DMODEL + gc] = f2bf(o[mi][di][r] * inv);
        }
      }
    }
}

// ---------------- host side ----------------
extern "C" void kernel_launch(void* const* d_in, const int* in_sizes, int n_in,
                              void* d_out, int out_size, void* d_ws, size_t ws_size,
                              hipStream_t stream) {
  const float* visual  = (const float*)d_in[0];
  const float* actions = (const float*)d_in[1];
  const float* states  = (const float*)d_in[2];
  const float* vproj_w = (const float*)d_in[3];
  const float* vproj_b = (const float*)d_in[4];
  const float* aproj_w = (const float*)d_in[5];
  const float* aproj_b = (const float*)d_in[6];
  const float* sproj_w = (const float*)d_in[7];
  const float* sproj_b = (const float*)d_in[8];
  const float* fembed  = (const float*)d_in[9];
  const float* qkv_w   = (const float*)d_in[10];
  const float* qkv_b   = (const float*)d_in[11];
  const float* ao_w    = (const float*)d_in[12];
  const float* ao_b    = (const float*)d_in[13];
  const float* ln1g    = (const float*)d_in[14];
  const float* ln1b    = (const float*)d_in[15];
  const float* ff1w    = (const float*)d_in[16];
  const float* ff1b    = (const float*)d_in[17];
  const float* ff2w    = (const float*)d_in[18];
  const float* ff2b    = (const float*)d_in[19];
  const float* ln2g    = (const float*)d_in[20];
  const float* ln2b    = (const float*)d_in[21];
  const float* ong     = (const float*)d_in[22];
  const float* onb     = (const float*)d_in[23];
  const float* opw     = (const float*)d_in[24];
  const float* opb     = (const float*)d_in[25];

  // workspace layout (~81.9 MB)
  char* ws = (char*)d_ws;
  float* x   = (float*)ws;  ws += (size_t)SEQ * DMODEL * 4;    // fp32 residual (14.2 MB)
  u16*  h    = (u16*)ws;    ws += (size_t)MPAD * DMODEL * 2;   // bf16 LN out / ctx (7.3 MB)
  u16*  ctx  = h;                                              // alias (disjoint in time)
  u16*  qkvb = (u16*)ws;    ws += (size_t)MPAD * 2304 * 2;     // (21.8 MB)
  u16*  fbuf = (u16*)ws;    ws += (size_t)MPAD * FFDIM * 2;    // FF intermediate (29.1 MB)
  u16*  visbf = fbuf;                                          // alias (pre-loop only)
  u16*  vt   = fbuf;                                           // alias (attn phase only)
  u16*  wbf  = (u16*)ws;    ws += (size_t)4718592 * 2;         // bf16 weights (9.4 MB)

  dim3 blk(256);
  const int MT = 37;  // SEQ tiles of 128 (MPAD/128)

  // ---- pre ----
  conv2_kernel<<<dim3((MVIS * VD) / 8 / 256), blk, 0, stream>>>(
      visual, visbf, (MVIS * VD) / 8, nullptr, nullptr, 0);
  conv2_kernel<<<dim3((DMODEL * VD) / 8 / 256), blk, 0, stream>>>(
      vproj_w, wbf, (DMODEL * VD) / 8, nullptr, nullptr, 0);
  gemm_bt<EPI_VIS><<<dim3(MVIS / 128, DMODEL / 128), blk, 0, stream>>>(
      visbf, wbf, vproj_b, nullptr, x, fembed, MVIS, DMODEL, VD);
  actsta_kernel<<<dim3(16), blk, 0, stream>>>(
      actions, states, aproj_w, aproj_b, sproj_w, sproj_b, x);

  const int nQKV8 = 2304 * 768 / 8;   // 221184
  const int nAO8  = 768 * 768 / 8;    //  73728
  const int nFF8  = 3072 * 768 / 8;   // 294912
  for (int l = 0; l < NLAY; l++) {
    conv2_kernel<<<dim3((nQKV8 + nAO8) / 256), blk, 0, stream>>>(
        qkv_w + (size_t)l * 2304 * 768, wbf, nQKV8,
        ao_w + (size_t)l * 768 * 768, wbf + 1769472, nAO8);
    ln_kernel<<<dim3(SEQ), blk, 0, stream>>>(x, h, ln1g + l * DMODEL, ln1b + l * DMODEL, 0);
    gemm_bt<EPI_BF><<<dim3(MT, 2304 / 128), blk, 0, stream>>>(
        h, wbf, qkv_b + (size_t)l * 2304, qkvb, nullptr, nullptr, SEQ, 2304, DMODEL);
    transpose_v_kernel<<<dim3(MT, NHEAD), blk, 0, stream>>>(qkvb, vt);
    attn_kernel<<<dim3(MT, NHEAD), blk, 0, stream>>>(qkvb, vt, ctx);
    gemm_bt<EPI_RES><<<dim3(MT, DMODEL / 128), blk, 0, stream>>>(
        ctx, wbf + 1769472, ao_b + (size_t)l * DMODEL, nullptr, x, nullptr, SEQ, DMODEL, DMODEL);
    ln_kernel<<<dim3(SEQ), blk, 0, stream>>>(x, h, ln2g + l * DMODEL, ln2b + l * DMODEL, 0);
    conv2_kernel<<<dim3((2 * nFF8) / 256), blk, 0, stream>>>(
        ff1w + (size_t)l * FFDIM * DMODEL, wbf, nFF8,
        ff2w + (size_t)l * DMODEL * FFDIM, wbf + 2359296, nFF8);
    gemm_bt<EPI_GELU><<<dim3(MT, FFDIM / 128), blk, 0, stream>>>(
        h, wbf, ff1b + (size_t)l * FFDIM, fbuf, nullptr, nullptr, SEQ, FFDIM, DMODEL);
    gemm_bt<EPI_RES><<<dim3(MT, DMODEL / 128), blk, 0, stream>>>(
        fbuf, wbf + 2359296, ff2b + (size_t)l * DMODEL, nullptr, x, nullptr, SEQ, DMODEL, FFDIM);
  }

  // ---- post ----
  ln_kernel<<<dim3(MVIS), blk, 0, stream>>>(x, h, ong, onb, 1);
  conv2_kernel<<<dim3((VD * DMODEL) / 8 / 256), blk, 0, stream>>>(
      opw, wbf, (VD * DMODEL) / 8, nullptr, nullptr, 0);
  gemm_bt<EPI_OUT><<<dim3(MVIS / 128, VD / 128), blk, 0, stream>>>(
      h, wbf, opb, nullptr, (float*)d_out, nullptr, MVIS, VD, DMODEL);
}

// Round 3
// 5029.951 us; speedup vs baseline: 1.6783x; 1.3213x over previous
//
#include <hip/hip_runtime.h>
#include <cstdint>
#include <cstddef>

// ---------------- problem constants ----------------
#define PPF   576
#define TPF   578
#define DMODEL 768
#define VD    1024
#define NLAY  12
#define NHEAD 12
#define HDIM  64
#define FFDIM 3072
#define TFRM  8
#define SEQ   4624           // TFRM*TPF
#define MVIS  4608           // TFRM*PPF
#define MPAD  4736           // 37*128, padded row count
#define SPAD  4736

typedef unsigned short u16;
typedef unsigned int   u32;
typedef __bf16 bf16_t;
typedef bf16_t bf16x8 __attribute__((ext_vector_type(8)));
typedef bf16_t bf16x4v __attribute__((ext_vector_type(4)));
typedef float  f32x4  __attribute__((ext_vector_type(4)));

__device__ __forceinline__ u16 f2bf(float f) {
  u32 u = __builtin_bit_cast(u32, f);
  return (u16)((u + 0x7fffu + ((u >> 16) & 1u)) >> 16);
}
__device__ __forceinline__ f32x4 mfma_bf16(bf16x8 a, bf16x8 b, f32x4 c) {
  return __builtin_amdgcn_mfma_f32_16x16x32_bf16(a, b, c, 0, 0, 0);
}

// async global->LDS, 16 B per lane; LDS dest = wave-uniform base + lane*16
typedef __attribute__((address_space(3))) unsigned int lds_u32;
typedef const __attribute__((address_space(1))) unsigned int glb_u32;
__device__ __forceinline__ void async16(const void* g, void* l) {
  __builtin_amdgcn_global_load_lds((glb_u32*)g, (lds_u32*)l, 16, 0, 0);
}

// ---------------- fp32 -> bf16 converter (two regions per launch) ----------------
__global__ __launch_bounds__(256) void conv2_kernel(
    const float* __restrict__ s1, u16* __restrict__ d1, int n1_8,
    const float* __restrict__ s2, u16* __restrict__ d2, int n2_8) {
  int i = blockIdx.x * 256 + threadIdx.x;
  const float* s;
  u16* d;
  int j;
  if (i < n1_8) {
    s = s1; d = d1; j = i;
  } else {
    j = i - n1_8;
    if (j >= n2_8) return;
    s = s2; d = d2;
  }
  const float4* p = (const float4*)s + (size_t)j * 2;
  float4 a = p[0], b = p[1];
  uint4 o;
  o.x = (u32)f2bf(a.x) | ((u32)f2bf(a.y) << 16);
  o.y = (u32)f2bf(a.z) | ((u32)f2bf(a.w) << 16);
  o.z = (u32)f2bf(b.x) | ((u32)f2bf(b.y) << 16);
  o.w = (u32)f2bf(b.z) | ((u32)f2bf(b.w) << 16);
  ((uint4*)d)[j] = o;
}

// ---------------- action/state projection + RoPE -> x rows t*578+{0,1} ----------------
__global__ __launch_bounds__(256) void actsta_kernel(
    const float* __restrict__ actions, const float* __restrict__ states,
    const float* __restrict__ aw, const float* __restrict__ ab,
    const float* __restrict__ sw, const float* __restrict__ sb,
    float* __restrict__ x) {
  int t = blockIdx.x >> 1, which = blockIdx.x & 1;
  const float* in = which ? (states + t * 7) : (actions + t * 7);
  const float* W  = which ? sw : aw;
  const float* bb = which ? sb : ab;
  float iv[7];
#pragma unroll
  for (int a = 0; a < 7; a++) iv[a] = in[a];
  float* xr = x + (size_t)(t * TPF + which) * DMODEL;
  for (int i = threadIdx.x; i < DMODEL / 2; i += 256) {
    float e = bb[2 * i], o = bb[2 * i + 1];
#pragma unroll
    for (int a = 0; a < 7; a++) {
      e += iv[a] * W[(2 * i) * 7 + a];
      o += iv[a] * W[(2 * i + 1) * 7 + a];
    }
    float freq = __expf((-2.0f * (float)i / 768.0f) * 9.210340371976184f);
    float ang = (float)t * freq;
    float sn = sinf(ang), cs = cosf(ang);
    xr[2 * i]     = e * cs - o * sn;
    xr[2 * i + 1] = e * sn + o * cs;
  }
}

// ---------------- LayerNorm: fp32 x -> bf16 h (optionally framed-row gather) ----------------
__global__ __launch_bounds__(256) void ln_kernel(
    const float* __restrict__ x, u16* __restrict__ h,
    const float* __restrict__ g, const float* __restrict__ b, int framed) {
  int row = blockIdx.x;
  int src = framed ? ((row / PPF) * TPF + 2 + (row % PPF)) : row;
  const float* xr = x + (size_t)src * DMODEL;
  int tid = threadIdx.x;
  float v0 = xr[tid], v1 = xr[tid + 256], v2 = xr[tid + 512];
  float s  = v0 + v1 + v2;
  float s2 = v0 * v0 + v1 * v1 + v2 * v2;
#pragma unroll
  for (int off = 32; off > 0; off >>= 1) {
    s  += __shfl_down(s, off);
    s2 += __shfl_down(s2, off);
  }
  __shared__ float red[8];
  int wv = tid >> 6;
  if ((tid & 63) == 0) { red[wv] = s; red[4 + wv] = s2; }
  __syncthreads();
  s  = red[0] + red[1] + red[2] + red[3];
  s2 = red[4] + red[5] + red[6] + red[7];
  float mu  = s * (1.0f / DMODEL);
  float var = s2 * (1.0f / DMODEL) - mu * mu;
  float rs  = rsqrtf(var + 1e-5f);
  u16* hr = h + (size_t)row * DMODEL;
  hr[tid]       = f2bf((v0 - mu) * rs * g[tid]       + b[tid]);
  hr[tid + 256] = f2bf((v1 - mu) * rs * g[tid + 256] + b[tid + 256]);
  hr[tid + 512] = f2bf((v2 - mu) * rs * g[tid + 512] + b[tid + 512]);
}

// ---------------- epilogue variants ----------------
enum { EPI_BF = 0, EPI_GELU = 1, EPI_RES = 2, EPI_VIS = 3, EPI_OUT = 4 };

template <int EPI>
__device__ __forceinline__ void gemm_epi(
    int gr, int gc, int M, int N, float v,
    u16* __restrict__ outb, float* __restrict__ outf, const float* __restrict__ fe) {
  if (gr >= M) return;
  if constexpr (EPI == EPI_BF) {
    outb[(size_t)gr * N + gc] = f2bf(v);
  } else if constexpr (EPI == EPI_GELU) {
    float gl = 0.5f * v * (1.0f + erff(v * 0.70710678118654752f));
    outb[(size_t)gr * N + gc] = f2bf(gl);
  } else if constexpr (EPI == EPI_RES) {
    outf[(size_t)gr * N + gc] += v;
  } else if constexpr (EPI == EPI_VIS) {
    int t = gr / PPF, p = gr % PPF;
    outf[(size_t)(t * TPF + 2 + p) * DMODEL + gc] = v + fe[(size_t)t * DMODEL + gc];
  } else {  // EPI_OUT
    outf[(size_t)gr * N + gc] = v;
  }
}

// ---------------- bf16 MFMA GEMM 128x128 (m97 structure): out[M,N] = A[M,K]*B[N,K]^T ----------------
template <int EPI>
__global__ __launch_bounds__(256) void gemm_bt(
    const u16* __restrict__ A, const u16* __restrict__ B,
    const float* __restrict__ bias, u16* __restrict__ outb,
    float* __restrict__ outf, const float* __restrict__ fe,
    int M, int N, int K) {
  __shared__ __align__(16) u16 As[128 * 32];
  __shared__ __align__(16) u16 Bs[128 * 32];
  const int tid = threadIdx.x;
  const int m0 = blockIdx.x * 128, n0 = blockIdx.y * 128;
  const int wv = tid >> 6, lane = tid & 63;
  const int fm = lane & 15, fq = lane >> 4;
  const int moff = (wv & 1) * 64, noff = (wv >> 1) * 64;

  f32x4 acc[4][4];
#pragma unroll
  for (int i = 0; i < 4; i++)
#pragma unroll
    for (int j = 0; j < 4; j++) acc[i][j] = f32x4{0.f, 0.f, 0.f, 0.f};

  const int srow = wv * 32 + (lane >> 2);
  const int scol = (lane & 3) * 8;
  const u16* ga = A + (size_t)(m0 + srow) * K + scol;
  const u16* gb = B + (size_t)(n0 + srow) * K + scol;
  u16* lA = As + (wv * 32) * 32;
  u16* lB = Bs + (wv * 32) * 32;
  const size_t row16 = (size_t)16 * K;

  for (int k0 = 0; k0 < K; k0 += 32) {
    async16(ga + k0,         lA);
    async16(ga + row16 + k0, lA + 16 * 32);
    async16(gb + k0,         lB);
    async16(gb + row16 + k0, lB + 16 * 32);
    __syncthreads();
    bf16x8 af[4], bfv[4];
#pragma unroll
    for (int mi = 0; mi < 4; mi++)
      af[mi] = *(const bf16x8*)&As[(moff + mi * 16 + fm) * 32 + fq * 8];
#pragma unroll
    for (int ni = 0; ni < 4; ni++)
      bfv[ni] = *(const bf16x8*)&Bs[(noff + ni * 16 + fm) * 32 + fq * 8];
#pragma unroll
    for (int mi = 0; mi < 4; mi++)
#pragma unroll
      for (int ni = 0; ni < 4; ni++)
        acc[mi][ni] = mfma_bf16(af[mi], bfv[ni], acc[mi][ni]);
    __syncthreads();
  }
#pragma unroll
  for (int mi = 0; mi < 4; mi++)
#pragma unroll
    for (int r = 0; r < 4; r++) {
      int gr = m0 + moff + mi * 16 + fq * 4 + r;
#pragma unroll
      for (int ni = 0; ni < 4; ni++) {
        int gc = n0 + noff + ni * 16 + fm;
        gemm_epi<EPI>(gr, gc, M, N, acc[mi][ni][r] + bias[gc], outb, outf, fe);
      }
    }
}

// ---------------- bf16 MFMA GEMM 64x128: for N=768/1024 cases (2x grid) ----------------
template <int EPI>
__global__ __launch_bounds__(256) void gemm_bt64(
    const u16* __restrict__ A, const u16* __restrict__ B,
    const float* __restrict__ bias, u16* __restrict__ outb,
    float* __restrict__ outf, const float* __restrict__ fe,
    int M, int N, int K) {
  __shared__ __align__(16) u16 As[64 * 32];
  __shared__ __align__(16) u16 Bs[128 * 32];
  const int tid = threadIdx.x;
  const int m0 = blockIdx.x * 64, n0 = blockIdx.y * 128;
  const int wv = tid >> 6, lane = tid & 63;
  const int fm = lane & 15, fq = lane >> 4;
  const int moff = (wv & 1) * 32, noff = (wv >> 1) * 64;

  f32x4 acc[2][4];
#pragma unroll
  for (int i = 0; i < 2; i++)
#pragma unroll
    for (int j = 0; j < 4; j++) acc[i][j] = f32x4{0.f, 0.f, 0.f, 0.f};

  const int scol = (lane & 3) * 8;
  const u16* ga = A + (size_t)(m0 + wv * 16 + (lane >> 2)) * K + scol;
  const u16* gb = B + (size_t)(n0 + wv * 32 + (lane >> 2)) * K + scol;
  u16* lA = As + (wv * 16) * 32;
  u16* lB = Bs + (wv * 32) * 32;
  const size_t row16 = (size_t)16 * K;

  for (int k0 = 0; k0 < K; k0 += 32) {
    async16(ga + k0,         lA);
    async16(gb + k0,         lB);
    async16(gb + row16 + k0, lB + 16 * 32);
    __syncthreads();
    bf16x8 af[2], bfv[4];
#pragma unroll
    for (int mi = 0; mi < 2; mi++)
      af[mi] = *(const bf16x8*)&As[(moff + mi * 16 + fm) * 32 + fq * 8];
#pragma unroll
    for (int ni = 0; ni < 4; ni++)
      bfv[ni] = *(const bf16x8*)&Bs[(noff + ni * 16 + fm) * 32 + fq * 8];
#pragma unroll
    for (int mi = 0; mi < 2; mi++)
#pragma unroll
      for (int ni = 0; ni < 4; ni++)
        acc[mi][ni] = mfma_bf16(af[mi], bfv[ni], acc[mi][ni]);
    __syncthreads();
  }
#pragma unroll
  for (int mi = 0; mi < 2; mi++)
#pragma unroll
    for (int r = 0; r < 4; r++) {
      int gr = m0 + moff + mi * 16 + fq * 4 + r;
#pragma unroll
      for (int ni = 0; ni < 4; ni++) {
        int gc = n0 + noff + ni * 16 + fm;
        gemm_epi<EPI>(gr, gc, M, N, acc[mi][ni][r] + bias[gc], outb, outf, fe);
      }
    }
}

// ---------------- V transpose: qkvb[s][1536+h*64+d] -> vt[h][d][s] ----------------
__global__ __launch_bounds__(256) void transpose_v_kernel(
    const u16* __restrict__ qkv, u16* __restrict__ vt) {
  const int hd = blockIdx.y;
  const int d = threadIdx.x & 63, sq = threadIdx.x >> 6;
  const int s0 = blockIdx.x * 128 + sq * 32;
  const u16* src = qkv + (size_t)s0 * 2304 + 2 * DMODEL + hd * 64 + d;
  u16 buf[32];
#pragma unroll
  for (int j = 0; j < 32; j++) buf[j] = src[(size_t)j * 2304];
  u16* dst = vt + (size_t)(hd * 64 + d) * SPAD + s0;
#pragma unroll
  for (int c = 0; c < 4; c++) {
    uint4 o;
    o.x = (u32)buf[c * 8 + 0] | ((u32)buf[c * 8 + 1] << 16);
    o.y = (u32)buf[c * 8 + 2] | ((u32)buf[c * 8 + 3] << 16);
    o.z = (u32)buf[c * 8 + 4] | ((u32)buf[c * 8 + 5] << 16);
    o.w = (u32)buf[c * 8 + 6] | ((u32)buf[c * 8 + 7] << 16);
    *(uint4*)(dst + c * 8) = o;
  }
}

// ---------------- flash attention, S^T orientation ----------------
// block = (128 q, head); wave = 32 q; 64-key tiles; K/V double-buffered via
// global_load_lds with XOR chunk swizzle (chunk c of row r at phys c^(r&7));
// one barrier per tile, prefetch issued after barrier (true async pipeline).
__global__ __launch_bounds__(256, 3) void attn_kernel(
    const u16* __restrict__ qkv, const u16* __restrict__ vt, u16* __restrict__ ctx) {
  __shared__ __align__(16) u16 Ks[2][64 * 64];   // [key][d], swizzled
  __shared__ __align__(16) u16 Vts[2][64 * 64];  // [d][key], swizzled
  __shared__ __align__(16) u16 Ps[4][32 * 72];   // per-wave P[q][key], pad 72
  const int qt = 36 - blockIdx.x, hd = blockIdx.y;
  const int tid = threadIdx.x, wv = tid >> 6, lane = tid & 63;
  const int fm = lane & 15, fq = lane >> 4;
  const int q0 = qt * 128 + wv * 32;
  const float scale2 = 0.18033688011112042f;  // (1/8) * log2(e)

  // Q as MFMA B-operand: lane holds Q[q=fm][d=fq*8..+7]
  bf16x8 qf[2][2];
#pragma unroll
  for (int bq = 0; bq < 2; bq++)
#pragma unroll
    for (int dk = 0; dk < 2; dk++)
      qf[bq][dk] = *(const bf16x8*)&qkv[(size_t)(q0 + bq * 16 + fm) * 2304 + hd * 64 + dk * 32 + fq * 8];
  int lim[2];
#pragma unroll
  for (int bq = 0; bq < 2; bq++)
    lim[bq] = ((q0 + bq * 16 + fm) / TPF + 1) * TPF;

  f32x4 o[2][4];
#pragma unroll
  for (int mi = 0; mi < 2; mi++)
#pragma unroll
    for (int di = 0; di < 4; di++) o[mi][di] = f32x4{0.f, 0.f, 0.f, 0.f};
  float mrow[2] = {-1e38f, -1e38f}, lrow[2] = {0.f, 0.f};

  const int qmax = min(qt * 128 + 127, SEQ - 1);
  const int nkv = (qmax / TPF + 1) * TPF;
  const int wlim = (min(q0 + 31, SEQ - 1) / TPF + 1) * TPF;
  const int ntiles = (nkv + 63) >> 6;

  // staging maps: lane covers row sr (of 8), phys chunk sc; global chunk = sc^sr
  const int sr = lane >> 3, sc = lane & 7;
  const u16* gK = qkv + (size_t)(wv * 16 + sr) * 2304 + DMODEL + hd * 64 + ((sc ^ sr) * 8);
  const u16* gV = vt + (size_t)(hd * 64 + wv * 16 + sr) * SPAD + ((sc ^ sr) * 8);

  // prefetch tile 0
  async16(gK,                     &Ks[0][(wv * 16) * 64]);
  async16(gK + (size_t)8 * 2304,  &Ks[0][(wv * 16 + 8) * 64]);
  async16(gV,                     &Vts[0][(wv * 16) * 64]);
  async16(gV + (size_t)8 * SPAD,  &Vts[0][(wv * 16 + 8) * 64]);

  for (int t = 0; t < ntiles; t++) {
    const int kb = t << 6;
    const int buf = t & 1;
    __syncthreads();
    const int kb2 = kb + 64;
    if (kb2 < nkv) {
      const int b2 = buf ^ 1;
      async16(gK + (size_t)kb2 * 2304,        &Ks[b2][(wv * 16) * 64]);
      async16(gK + (size_t)(kb2 + 8) * 2304,  &Ks[b2][(wv * 16 + 8) * 64]);
      async16(gV + kb2,                       &Vts[b2][(wv * 16) * 64]);
      async16(gV + kb2 + (size_t)8 * SPAD,    &Vts[b2][(wv * 16 + 8) * 64]);
    }
    if (kb >= wlim) continue;
    const u16* kbuf = Ks[buf];
    const u16* vbuf = Vts[buf];

    // S^T[64 key][32 q] = K Q^T  (m=key, n=q)
    f32x4 sA[4][2];
#pragma unroll
    for (int bk = 0; bk < 4; bk++) {
      sA[bk][0] = f32x4{0.f, 0.f, 0.f, 0.f};
      sA[bk][1] = f32x4{0.f, 0.f, 0.f, 0.f};
    }
#pragma unroll
    for (int dk = 0; dk < 2; dk++)
#pragma unroll
      for (int bk = 0; bk < 4; bk++) {
        bf16x8 kv = *(const bf16x8*)&kbuf[(bk * 16 + fm) * 64 + (((dk * 4 + fq) ^ (fm & 7)) * 8)];
        sA[bk][0] = mfma_bf16(kv, qf[0][dk], sA[bk][0]);
        sA[bk][1] = mfma_bf16(kv, qf[1][dk], sA[bk][1]);
      }

    // online softmax: lane holds 16 keys (bk,r) for q = bq*16+fm; reduce over fq
    float al[2];
#pragma unroll
    for (int bq = 0; bq < 2; bq++) {
      float vv[16];
      float mx = -1e38f;
#pragma unroll
      for (int bk = 0; bk < 4; bk++)
#pragma unroll
        for (int r = 0; r < 4; r++) {
          float v = sA[bk][bq][r];
          int kidx = kb + bk * 16 + fq * 4 + r;
          if (kidx >= lim[bq]) v = -1e38f;
          vv[bk * 4 + r] = v;
          mx = fmaxf(mx, v);
        }
      mx = fmaxf(mx, __shfl_xor(mx, 16));
      mx = fmaxf(mx, __shfl_xor(mx, 32));
      float mn = fmaxf(mrow[bq], mx);
      al[bq] = exp2f((mrow[bq] - mn) * scale2);
      mrow[bq] = mn;
      float c = mn * scale2;
      float sum = 0.f;
#pragma unroll
      for (int bk = 0; bk < 4; bk++) {
        bf16x4v pk;
#pragma unroll
        for (int r = 0; r < 4; r++) {
          float p = exp2f(__builtin_fmaf(vv[bk * 4 + r], scale2, -c));
          sum += p;
          pk[r] = (bf16_t)p;
        }
        *(bf16x4v*)&Ps[wv][(bq * 16 + fm) * 72 + bk * 16 + fq * 4] = pk;  // ds_write_b64
      }
      sum += __shfl_xor(sum, 16);
      sum += __shfl_xor(sum, 32);
      lrow[bq] = lrow[bq] * al[bq] + sum;
    }
    // rescale O (O rows are q = mi*16 + fq*4 + r -> fetch al from lane fq*4+r)
#pragma unroll
    for (int mi = 0; mi < 2; mi++)
#pragma unroll
      for (int r = 0; r < 4; r++) {
        float a = __shfl(al[mi], fq * 4 + r);
#pragma unroll
        for (int di = 0; di < 4; di++) o[mi][di][r] *= a;
      }
    // PV: O[32q][64d] += P[32q][64k] * V^T
    bf16x8 pf[2][2];
#pragma unroll
    for (int mi = 0; mi < 2; mi++)
#pragma unroll
      for (int kk = 0; kk < 2; kk++)
        pf[mi][kk] = *(const bf16x8*)&Ps[wv][(mi * 16 + fm) * 72 + kk * 32 + fq * 8];
#pragma unroll
    for (int di = 0; di < 4; di++)
#pragma unroll
      for (int kk = 0; kk < 2; kk++) {
        bf16x8 vf = *(const bf16x8*)&vbuf[(di * 16 + fm) * 64 + (((kk * 4 + fq) ^ (fm & 7)) * 8)];
        o[0][di] = mfma_bf16(pf[0][kk], vf, o[0][di]);
        o[1][di] = mfma_bf16(pf[1][kk], vf, o[1][di]);
      }
  }
  // write ctx
#pragma unroll
  for (int mi = 0; mi < 2; mi++)
#pragma unroll
    for (int r = 0; r < 4; r++) {
      float l = __shfl(lrow[mi], fq * 4 + r);
      float inv = (l > 0.f) ? 1.f / l : 0.f;
      int gr = q0 + mi * 16 + fq * 4 + r;
      if (gr < SEQ) {
#pragma unroll
        for (int di = 0; di < 4; di++)
          ctx[(size_t)gr * DMODEL + hd * 64 + di * 16 + fm] = f2bf(o[mi][di][r] * inv);
      }
    }
}

// ---------------- host side ----------------
extern "C" void kernel_launch(void* const* d_in, const int* in_sizes, int n_in,
                              void* d_out, int out_size, void* d_ws, size_t ws_size,
                              hipStream_t stream) {
  const float* visual  = (const float*)d_in[0];
  const float* actions = (const float*)d_in[1];
  const float* states  = (const float*)d_in[2];
  const float* vproj_w = (const float*)d_in[3];
  const float* vproj_b = (const float*)d_in[4];
  const float* aproj_w = (const float*)d_in[5];
  const float* aproj_b = (const float*)d_in[6];
  const float* sproj_w = (const float*)d_in[7];
  const float* sproj_b = (const float*)d_in[8];
  const float* fembed  = (const float*)d_in[9];
  const float* qkv_w   = (const float*)d_in[10];
  const float* qkv_b   = (const float*)d_in[11];
  const float* ao_w    = (const float*)d_in[12];
  const float* ao_b    = (const float*)d_in[13];
  const float* ln1g    = (const float*)d_in[14];
  const float* ln1b    = (const float*)d_in[15];
  const float* ff1w    = (const float*)d_in[16];
  const float* ff1b    = (const float*)d_in[17];
  const float* ff2w    = (const float*)d_in[18];
  const float* ff2b    = (const float*)d_in[19];
  const float* ln2g    = (const float*)d_in[20];
  const float* ln2b    = (const float*)d_in[21];
  const float* ong     = (const float*)d_in[22];
  const float* onb     = (const float*)d_in[23];
  const float* opw     = (const float*)d_in[24];
  const float* opb     = (const float*)d_in[25];

  // workspace layout (~81.9 MB)
  char* ws = (char*)d_ws;
  float* x   = (float*)ws;  ws += (size_t)SEQ * DMODEL * 4;    // fp32 residual
  u16*  h    = (u16*)ws;    ws += (size_t)MPAD * DMODEL * 2;   // bf16 LN out / ctx
  u16*  ctx  = h;                                              // alias (disjoint in time)
  u16*  qkvb = (u16*)ws;    ws += (size_t)MPAD * 2304 * 2;
  u16*  fbuf = (u16*)ws;    ws += (size_t)MPAD * FFDIM * 2;    // FF intermediate
  u16*  visbf = fbuf;                                          // alias (pre-loop only)
  u16*  vt   = fbuf;                                           // alias (attn phase only)
  u16*  wbf  = (u16*)ws;    ws += (size_t)4718592 * 2;         // bf16 weights

  dim3 blk(256);
  const int MT = 37;   // 128-row tiles
  const int MT64 = 74; // 64-row tiles

  // ---- pre ----
  conv2_kernel<<<dim3((MVIS * VD) / 8 / 256), blk, 0, stream>>>(
      visual, visbf, (MVIS * VD) / 8, nullptr, nullptr, 0);
  conv2_kernel<<<dim3((DMODEL * VD) / 8 / 256), blk, 0, stream>>>(
      vproj_w, wbf, (DMODEL * VD) / 8, nullptr, nullptr, 0);
  gemm_bt64<EPI_VIS><<<dim3(MVIS / 64, DMODEL / 128), blk, 0, stream>>>(
      visbf, wbf, vproj_b, nullptr, x, fembed, MVIS, DMODEL, VD);
  actsta_kernel<<<dim3(16), blk, 0, stream>>>(
      actions, states, aproj_w, aproj_b, sproj_w, sproj_b, x);

  const int nQKV8 = 2304 * 768 / 8;
  const int nAO8  = 768 * 768 / 8;
  const int nFF8  = 3072 * 768 / 8;
  for (int l = 0; l < NLAY; l++) {
    conv2_kernel<<<dim3((nQKV8 + nAO8) / 256), blk, 0, stream>>>(
        qkv_w + (size_t)l * 2304 * 768, wbf, nQKV8,
        ao_w + (size_t)l * 768 * 768, wbf + 1769472, nAO8);
    ln_kernel<<<dim3(SEQ), blk, 0, stream>>>(x, h, ln1g + l * DMODEL, ln1b + l * DMODEL, 0);
    gemm_bt<EPI_BF><<<dim3(MT, 2304 / 128), blk, 0, stream>>>(
        h, wbf, qkv_b + (size_t)l * 2304, qkvb, nullptr, nullptr, SEQ, 2304, DMODEL);
    transpose_v_kernel<<<dim3(MT, NHEAD), blk, 0, stream>>>(qkvb, vt);
    attn_kernel<<<dim3(MT, NHEAD), blk, 0, stream>>>(qkvb, vt, ctx);
    gemm_bt64<EPI_RES><<<dim3(MT64, DMODEL / 128), blk, 0, stream>>>(
        ctx, wbf + 1769472, ao_b + (size_t)l * DMODEL, nullptr, x, nullptr, SEQ, DMODEL, DMODEL);
    ln_kernel<<<dim3(SEQ), blk, 0, stream>>>(x, h, ln2g + l * DMODEL, ln2b + l * DMODEL, 0);
    conv2_kernel<<<dim3((2 * nFF8) / 256), blk, 0, stream>>>(
        ff1w + (size_t)l * FFDIM * DMODEL, wbf, nFF8,
        ff2w + (size_t)l * DMODEL * FFDIM, wbf + 2359296, nFF8);
    gemm_bt<EPI_GELU><<<dim3(MT, FFDIM / 128), blk, 0, stream>>>(
        h, wbf, ff1b + (size_t)l * FFDIM, fbuf, nullptr, nullptr, SEQ, FFDIM, DMODEL);
    gemm_bt64<EPI_RES><<<dim3(MT64, DMODEL / 128), blk, 0, stream>>>(
        fbuf, wbf + 2359296, ff2b + (size_t)l * DMODEL, nullptr, x, nullptr, SEQ, DMODEL, FFDIM);
  }

  // ---- post ----
  ln_kernel<<<dim3(MVIS), blk, 0, stream>>>(x, h, ong, onb, 1);
  conv2_kernel<<<dim3((VD * DMODEL) / 8 / 256), blk, 0, stream>>>(
      opw, wbf, (VD * DMODEL) / 8, nullptr, nullptr, 0);
  gemm_bt64<EPI_OUT><<<dim3(MVIS / 64, VD / 128), blk, 0, stream>>>(
      h, wbf, opb, nullptr, (float*)d_out, nullptr, MVIS, VD, DMODEL);
}